// Round 3
// baseline (304.398 us; speedup 1.0000x reference)
//
#include <hip/hip_runtime.h>
#include <hip/hip_bf16.h>
#include <math.h>

#define NN 50000
#define NE 800000
#define NET (NE + NN)   // edges + self loops
#define FIN 310
#define HD 128
#define NHID 64
#define NCLS 2
#define NG 128
#define NEG_SLOPE 0.2f
#define KP1 320
#define KP2 128

#define SLOTS 64                    // max degree (Poisson(16)+1; P(>63) ~ 1e-22)
#define NPART 8
#define PART_SZ (NN / NPART)        // 6250
#define EPB 4096
#define NSLICE ((NET + EPB - 1) / EPB)   // 208
#define NSC (NSLICE * NPART)             // 1664 scatter blocks
#define GB1 ((NN + 63) / 64)             // 782 gemm blocks

#define SELU_SCALE 1.0507009873554804934193349852946f
#define SELU_ALPHA 1.6732632423543772848170429916717f

typedef short bf16x8 __attribute__((ext_vector_type(8)));
typedef float f32x4 __attribute__((ext_vector_type(4)));

__device__ __forceinline__ float selu(float x) {
    return SELU_SCALE * (x > 0.f ? x : SELU_ALPHA * (__expf(x) - 1.f));
}
__device__ __forceinline__ float lrelu(float x) {
    return x > 0.f ? x : NEG_SLOPE * x;
}
__device__ __forceinline__ unsigned short f2bf(float f) {
    unsigned int u = __float_as_uint(f);
    u = (u + 0x7fffu + ((u >> 16) & 1u)) >> 16;
    return (unsigned short)u;
}
__device__ __forceinline__ float bf2f(unsigned short b) {
    return __uint_as_float(((unsigned int)b) << 16);
}

// ---------------- W cast+transpose (fragment-packed) + cursor zero ------------
// Wp[kb][n][8]: the B-fragment for (kb, quad, l16) is 16B contiguous.

__global__ void k_castW(const float* __restrict__ W1, const float* __restrict__ W2,
                        unsigned short* __restrict__ W1p, unsigned short* __restrict__ W2p,
                        int* __restrict__ cursor) {
    int i = blockIdx.x * blockDim.x + threadIdx.x;
    if (i < NN) cursor[i] = 0;
    const int N1 = HD * KP1;
    if (i < N1) {
        int n = i / KP1, k = i % KP1;
        unsigned short v = (k < FIN) ? f2bf(W1[(size_t)k * HD + n]) : (unsigned short)0;
        W1p[((k >> 3) * HD + n) * 8 + (k & 7)] = v;
    } else if (i - N1 < HD * KP2) {
        int j = i - N1;
        int n = j / KP2, k = j % KP2;
        W2p[((k >> 3) * HD + n) * 8 + (k & 7)] = f2bf(W2[(size_t)k * HD + n]);
    }
}

// NOTE: cursor zeroing needs i < NN coverage: grid must span >= NN threads.
#define CWB ((NN + 255) / 256)   // 196 blocks covers both W casts (57344 > 40960+16384? no:
// HD*KP1=40960, HD*KP2=16384, total 57344 threads needed for W; NN=50000 for cursor.
// Use max of both: 57344 -> 224 blocks.
#define CASTW_GRID (((HD * (KP1 + KP2)) + 255) / 256)   // 224; 224*256=57344 >= NN too

// ---------------- slotted scatter body (r8 variant: space-partition) ----------

__device__ __forceinline__ void scatter_body(int slice, const int* __restrict__ ei,
                                             int* __restrict__ cursor,
                                             unsigned short* __restrict__ slots,
                                             int part) {
    int lo = part * PART_SZ;
    int base = slice * EPB + threadIdx.x;
#pragma unroll
    for (int k = 0; k < EPB / 256; ++k) {
        int i = base + k * 256;
        if (i >= NET) break;
        int d = (i < NE) ? ei[NE + i] : (i - NE);
        if ((unsigned)(d - lo) < (unsigned)PART_SZ) {
            int s = (i < NE) ? ei[i] : d;
            int pos = atomicAdd(&cursor[d], 1) & (SLOTS - 1);
            slots[(size_t)d * SLOTS + pos] = (unsigned short)s;
        }
    }
}

// ---------------- GEMM epilogue (row-major bf16 C + fused attention dots) -----

#define RGEMM_EPILOGUE                                                         \
    int gr_base = r0 + w * 16 + quad * 4;                                      \
    _Pragma("unroll")                                                          \
    for (int r = 0; r < 4; ++r) {                                              \
        int gr = gr_base + r;                                                  \
        if (gr < M) {                                                          \
            _Pragma("unroll")                                                  \
            for (int nt = 0; nt < 8; ++nt)                                     \
                C[(size_t)gr * HD + nt * 16 + l16] = f2bf(acc[nt][r]);         \
        }                                                                      \
    }                                                                          \
    _Pragma("unroll")                                                          \
    for (int r = 0; r < 4; ++r) {                                              \
        float s1 = 0.f, s2 = 0.f;                                              \
        _Pragma("unroll")                                                      \
        for (int nt = 0; nt < 8; ++nt) {                                       \
            int c = nt * 16 + l16;                                             \
            float v = acc[nt][r];                                              \
            s1 += v * a_src[c];                                                \
            s2 += v * a_dst[c];                                                \
        }                                                                      \
        _Pragma("unroll")                                                      \
        for (int off = 1; off < 16; off <<= 1) {                               \
            s1 += __shfl_xor(s1, off);                                         \
            s2 += __shfl_xor(s2, off);                                         \
        }                                                                      \
        int gr = gr_base + r;                                                  \
        if (l16 == 0 && gr < M) { asrcp[gr] = s1; adstp[gr] = s2; }            \
    }

// ---------------- merged: layer-1 fp32-direct GEMM || full adjacency scatter --
// A-path reads x fp32 directly (62 MB) instead of the castX round-trip
// (62 read + 32 write + 32 read = 126 MB). Explicit next-step register
// prefetch + full unroll hides the load latency under the 32 f2bf converts
// and 8 MFMAs of the current step (round-0's version was unroll-2, no
// prefetch -> serial chain; that, not VALU throughput, was its cost).
// float2 loads: row stride 1240 B is 8B- but not 16B-aligned.

__global__ __launch_bounds__(256) void k_pre(const float* __restrict__ A,
                                             const unsigned short* __restrict__ Bp,
                                             unsigned short* __restrict__ C,
                                             float* __restrict__ asrcp,
                                             float* __restrict__ adstp,
                                             const float* __restrict__ a_src,
                                             const float* __restrict__ a_dst,
                                             int M,
                                             const int* __restrict__ ei,
                                             int* __restrict__ cursor,
                                             unsigned short* __restrict__ slots) {
    if (blockIdx.x >= GB1) {
        int b = blockIdx.x - GB1;
        int part = (blockIdx.x + 2) & 7;   // == (b & 7); XCD-pinned partitions
        scatter_body(b >> 3, ei, cursor, slots, part);
        return;
    }
    int t = threadIdx.x;
    int lane = t & 63, w = t >> 6;
    int quad = lane >> 4, l16 = lane & 15;
    int r0 = blockIdx.x * 64;

    int grow = r0 + w * 16 + l16;
    int arow = min(grow, M - 1);
    const float* ap = A + (size_t)arow * FIN + quad * 8;

    f32x4 acc[8] = {};

    // prefetch step 0 (elements quad*8 .. quad*8+7; max 31+... = 31 < 310 safe)
    float2 c0 = *(const float2*)(ap + 0);
    float2 c1 = *(const float2*)(ap + 2);
    float2 c2 = *(const float2*)(ap + 4);
    float2 c3 = *(const float2*)(ap + 6);
#pragma unroll
    for (int k0 = 0; k0 < 288; k0 += 32) {
        // prefetch next full step (clamp: re-load of step 256 on last iter, L1-hit)
        int kn = (k0 < 256) ? k0 + 32 : 256;
        float2 n0 = *(const float2*)(ap + kn + 0);
        float2 n1 = *(const float2*)(ap + kn + 2);
        float2 n2 = *(const float2*)(ap + kn + 4);
        float2 n3 = *(const float2*)(ap + kn + 6);
        union { bf16x8 v; unsigned short u[8]; } af;
        af.u[0] = f2bf(c0.x); af.u[1] = f2bf(c0.y);
        af.u[2] = f2bf(c1.x); af.u[3] = f2bf(c1.y);
        af.u[4] = f2bf(c2.x); af.u[5] = f2bf(c2.y);
        af.u[6] = f2bf(c3.x); af.u[7] = f2bf(c3.y);
        const unsigned short* bbase = Bp + ((size_t)(k0 >> 3) + quad) * (HD * 8) + l16 * 8;
#pragma unroll
        for (int nt = 0; nt < 8; ++nt) {
            bf16x8 bfr = *(const bf16x8*)(bbase + nt * 128);
            acc[nt] = __builtin_amdgcn_mfma_f32_16x16x32_bf16(af.v, bfr, acc[nt], 0, 0, 0);
        }
        c0 = n0; c1 = n1; c2 = n2; c3 = n3;
    }
    {   // tail step k0 = 288: elements 288+quad*8+j, predicated vs FIN
        int kb = 288 + quad * 8;
        const float* rp = A + (size_t)arow * FIN;
        union { bf16x8 v; unsigned short u[8]; } af;
#pragma unroll
        for (int j = 0; j < 8; ++j)
            af.u[j] = (kb + j < FIN) ? f2bf(rp[kb + j]) : (unsigned short)0;
        const unsigned short* bbase = Bp + ((size_t)(288 >> 3) + quad) * (HD * 8) + l16 * 8;
#pragma unroll
        for (int nt = 0; nt < 8; ++nt) {
            bf16x8 bfr = *(const bf16x8*)(bbase + nt * 128);
            acc[nt] = __builtin_amdgcn_mfma_f32_16x16x32_bf16(af.v, bfr, acc[nt], 0, 0, 0);
        }
    }
    RGEMM_EPILOGUE
}

// ---------------- fused gat1 + gemm2 ------------------------------------------
// Block = 256 threads handles 64 nodes. Phase 1 (gat): one node per 16-lane
// group, 4 nodes/group sequentially; selu'd o1 rows land in a +8-padded LDS
// tile (272B stride). Phase 2: gemm<128> with A from LDS; writes h2 +
// layer-2 attention dots. No o1 global round-trip.

__global__ __launch_bounds__(256) void k_gatg2(const unsigned short* __restrict__ h,
                                               const float* __restrict__ asrc,
                                               const float* __restrict__ adst,
                                               const int* __restrict__ degv,
                                               const unsigned short* __restrict__ slots,
                                               const float* __restrict__ bias,
                                               const unsigned short* __restrict__ Bp,
                                               unsigned short* __restrict__ C,
                                               float* __restrict__ asrcp,
                                               float* __restrict__ adstp,
                                               const float* __restrict__ a_src,
                                               const float* __restrict__ a_dst,
                                               int M) {
    __shared__ unsigned short Al[64][136];   // 64 rows x 128 cols, +8 pad
    int t = threadIdx.x;
    int n0 = blockIdx.x * 64;
    {
        int wv = t >> 6;
        int lane = t & 63;
        int g = lane >> 4, l = lane & 15;
        int gid = wv * 4 + g;                // 0..15

        for (int it = 0; it < 4; ++it) {
            int node = n0 + it * 16 + gid;
            bool vn = node < NN;
            int cnt = vn ? min(degv[node], SLOTS) : 0;
            float adsti = vn ? adst[node] : 0.f;
            int s_c[4]; float p_c[4];
#pragma unroll
            for (int j = 0; j < 4; ++j) {
                int e = l + 16 * j;
                bool v = e < cnt;
                int s = v ? (int)slots[(size_t)node * SLOTS + e] : 0;
                s_c[j] = s;
                p_c[j] = v ? __expf(lrelu(asrc[s] + adsti)) : 0.f;
            }
            float den = p_c[0] + p_c[1] + p_c[2] + p_c[3];
#pragma unroll
            for (int off = 1; off < 16; off <<= 1) den += __shfl_xor(den, off, 16);

            // wave-uniform edge bound: no divergent shfl sourcing
            int mc = cnt;
            mc = max(mc, __shfl_xor(mc, 16));
            mc = max(mc, __shfl_xor(mc, 32));

            float2 acc2[4] = {};
#pragma unroll
            for (int j = 0; j < 4; ++j) {
                if (16 * j < mc) {
                    int quads = (min(mc - 16 * j, 16) + 3) >> 2;
                    for (int q = 0; q < quads; ++q) {
                        float pv[4]; uint4 hv[4];
#pragma unroll
                        for (int u = 0; u < 4; ++u) {
                            int e = q * 4 + u;                 // 0..15
                            int s = __shfl(s_c[j], e, 16);
                            pv[u] = __shfl(p_c[j], e, 16);     // 0 for padding
                            hv[u] = *(const uint4*)(h + (size_t)s * HD + l * 8);
                        }
#pragma unroll
                        for (int u = 0; u < 4; ++u) {
                            float p = pv[u];
                            unsigned int w0 = hv[u].x, w1 = hv[u].y, w2 = hv[u].z, w3 = hv[u].w;
                            acc2[0].x += p * __uint_as_float(w0 << 16);
                            acc2[0].y += p * __uint_as_float(w0 & 0xffff0000u);
                            acc2[1].x += p * __uint_as_float(w1 << 16);
                            acc2[1].y += p * __uint_as_float(w1 & 0xffff0000u);
                            acc2[2].x += p * __uint_as_float(w2 << 16);
                            acc2[2].y += p * __uint_as_float(w2 & 0xffff0000u);
                            acc2[3].x += p * __uint_as_float(w3 << 16);
                            acc2[3].y += p * __uint_as_float(w3 & 0xffff0000u);
                        }
                    }
                }
            }
            float inv = (den > 0.f) ? 1.f / den : 0.f;
            int c0 = l * 8;
            float4 b0 = *(const float4*)(bias + c0);
            float4 b1v = *(const float4*)(bias + c0 + 4);
            union { bf16x8 v; unsigned short u[8]; } o;
            o.u[0] = f2bf(selu(acc2[0].x * inv + b0.x));
            o.u[1] = f2bf(selu(acc2[0].y * inv + b0.y));
            o.u[2] = f2bf(selu(acc2[1].x * inv + b0.z));
            o.u[3] = f2bf(selu(acc2[1].y * inv + b0.w));
            o.u[4] = f2bf(selu(acc2[2].x * inv + b1v.x));
            o.u[5] = f2bf(selu(acc2[2].y * inv + b1v.y));
            o.u[6] = f2bf(selu(acc2[3].x * inv + b1v.z));
            o.u[7] = f2bf(selu(acc2[3].y * inv + b1v.w));
            *(bf16x8*)&Al[it * 16 + gid][c0] = o.v;
        }
    }
    __syncthreads();
    {
        int lane = t & 63, w = t >> 6;
        int quad = lane >> 4, l16 = lane & 15;
        int r0 = blockIdx.x * 64;
        int arow = w * 16 + l16;             // LDS-local row
        f32x4 acc[8] = {};
#pragma unroll
        for (int k0 = 0; k0 < KP2; k0 += 32) {
            bf16x8 af = *(const bf16x8*)&Al[arow][quad * 8 + k0];
            const unsigned short* bbase = Bp + ((size_t)(k0 >> 3) + quad) * (HD * 8) + l16 * 8;
#pragma unroll
            for (int nt = 0; nt < 8; ++nt) {
                bf16x8 bfr = *(const bf16x8*)(bbase + nt * 128);
                acc[nt] = __builtin_amdgcn_mfma_f32_16x16x32_bf16(af, bfr, acc[nt], 0, 0, 0);
            }
        }
        RGEMM_EPILOGUE
    }
}

// ---------------- GAT aggregation, standalone (layer 2) -----------------------

__global__ __launch_bounds__(256) void k_gat(const unsigned short* __restrict__ h,
                                             const float* __restrict__ asrc,
                                             const float* __restrict__ adst,
                                             const int* __restrict__ degv,
                                             const unsigned short* __restrict__ slots,
                                             const float* __restrict__ bias,
                                             unsigned short* __restrict__ out) {
    int node = blockIdx.x * 4 + (threadIdx.x >> 6);
    int lane = threadIdx.x & 63;
    if (node >= NN) return;
    int g = lane >> 4, cl = lane & 15;
    int deg = degv[node];
    float adsti = adst[node];

    float2 acc2[4] = {};

    int cnt = min(deg, SLOTS);
    int s_c = 0; float p_c = 0.f;
    if (lane < cnt) {
        s_c = slots[(size_t)node * SLOTS + lane];
        p_c = __expf(lrelu(asrc[s_c] + adsti));
    }
    float den_l = p_c;
    int nt = (cnt + 3) >> 2;   // edge-quads
    for (int t = 0; t < nt; t += 4) {
        float pv[4]; uint4 hv[4];
#pragma unroll
        for (int u = 0; u < 4; ++u) {
            int tt = t + u;
            bool valid = tt < nt;
            int e = (4 * tt + g) & 63;
            int s = __shfl(s_c, e);
            float p = __shfl(p_c, e);
            int sa = valid ? s : 0;
            pv[u] = valid ? p : 0.f;
            hv[u] = *(const uint4*)(h + (size_t)sa * HD + cl * 8);
        }
#pragma unroll
        for (int u = 0; u < 4; ++u) {
            float p = pv[u];
            unsigned int w0 = hv[u].x, w1 = hv[u].y, w2 = hv[u].z, w3 = hv[u].w;
            acc2[0].x += p * __uint_as_float(w0 << 16);
            acc2[0].y += p * __uint_as_float(w0 & 0xffff0000u);
            acc2[1].x += p * __uint_as_float(w1 << 16);
            acc2[1].y += p * __uint_as_float(w1 & 0xffff0000u);
            acc2[2].x += p * __uint_as_float(w2 << 16);
            acc2[2].y += p * __uint_as_float(w2 & 0xffff0000u);
            acc2[3].x += p * __uint_as_float(w3 << 16);
            acc2[3].y += p * __uint_as_float(w3 & 0xffff0000u);
        }
    }
#pragma unroll
    for (int k = 0; k < 4; ++k) {
        acc2[k].x += __shfl_xor(acc2[k].x, 16);
        acc2[k].y += __shfl_xor(acc2[k].y, 16);
        acc2[k].x += __shfl_xor(acc2[k].x, 32);
        acc2[k].y += __shfl_xor(acc2[k].y, 32);
    }
#pragma unroll
    for (int off = 32; off; off >>= 1)
        den_l += __shfl_xor(den_l, off);

    if (g == 0) {
        float inv = 1.f / den_l;
        int c0 = cl * 8;
        float4 b0 = *(const float4*)(bias + c0);
        float4 b1 = *(const float4*)(bias + c0 + 4);
        float v0 = selu(acc2[0].x * inv + b0.x);
        float v1 = selu(acc2[0].y * inv + b0.y);
        float v2 = selu(acc2[1].x * inv + b0.z);
        float v3 = selu(acc2[1].y * inv + b0.w);
        float v4 = selu(acc2[2].x * inv + b1.x);
        float v5 = selu(acc2[2].y * inv + b1.y);
        float v6 = selu(acc2[3].x * inv + b1.z);
        float v7 = selu(acc2[3].y * inv + b1.w);
        uint4 pk;
        pk.x = (unsigned int)f2bf(v0) | ((unsigned int)f2bf(v1) << 16);
        pk.y = (unsigned int)f2bf(v2) | ((unsigned int)f2bf(v3) << 16);
        pk.z = (unsigned int)f2bf(v4) | ((unsigned int)f2bf(v5) << 16);
        pk.w = (unsigned int)f2bf(v6) | ((unsigned int)f2bf(v7) << 16);
        *(uint4*)(out + (size_t)node * HD + c0) = pk;
    }
}

// ---------------- pooling + FC head (fused, one block per graph) ----------------

__device__ __forceinline__ int lower_bound_i(const int* a, int n, int key) {
    int lo = 0, hi = n;
    while (lo < hi) {
        int mid = (lo + hi) >> 1;
        if (a[mid] < key) lo = mid + 1; else hi = mid;
    }
    return lo;
}

__global__ __launch_bounds__(512) void k_poolfc(const unsigned short* __restrict__ x,
                                                const int* __restrict__ batch,
                                                const float* __restrict__ w1,
                                                const float* __restrict__ b1,
                                                const float* __restrict__ w2,
                                                const float* __restrict__ b2,
                                                float* __restrict__ out) {
    int g = blockIdx.x;
    int t = threadIdx.x;
    __shared__ int lo_s, hi_s;
    __shared__ float red[512];
    __shared__ float pooled_s[128];
    if (t == 0) {
        lo_s = lower_bound_i(batch, NN, g);
        hi_s = lower_bound_i(batch, NN, g + 1);
    }
    __syncthreads();
    int lo = lo_s, hi = hi_s;
    float acc = 0.f;
    for (int n = lo + (t >> 7); n < hi; n += 4)
        acc += bf2f(x[(size_t)n * HD + (t & 127)]);
    red[t] = acc;
    __syncthreads();
    if (t < 128) {
        float v = red[t] + red[t + 128] + red[t + 256] + red[t + 384];
        pooled_s[t] = selu(v / fmaxf((float)(hi - lo), 1.f));
    }
    __syncthreads();
    if (t < 64) {
        float z = 0.f;
#pragma unroll 8
        for (int k = 0; k < HD; ++k) z += pooled_s[k] * w1[k * NHID + t];
        z = selu(z + b1[t]);
        float p0 = z * w2[t * NCLS + 0];
        float p1 = z * w2[t * NCLS + 1];
        for (int off = 32; off; off >>= 1) {
            p0 += __shfl_down(p0, off);
            p1 += __shfl_down(p1, off);
        }
        if (t == 0) {
            float l0 = p0 + b2[0], l1 = p1 + b2[1];
            float m = fmaxf(l0, l1);
            float lse = m + __logf(__expf(l0 - m) + __expf(l1 - m));
            out[g * NCLS + 0] = l0 - lse;
            out[g * NCLS + 1] = l1 - lse;
        }
    }
}

// ---------------- launch ----------------

static inline size_t align_up(size_t v, size_t a) { return (v + a - 1) / a * a; }

extern "C" void kernel_launch(void* const* d_in, const int* in_sizes, int n_in,
                              void* d_out, int out_size, void* d_ws, size_t ws_size,
                              hipStream_t stream) {
    const float* x      = (const float*)d_in[0];
    const int*   ei     = (const int*)d_in[1];
    const int*   batch  = (const int*)d_in[2];
    const float* W1     = (const float*)d_in[3];
    const float* a_src1 = (const float*)d_in[4];
    const float* a_dst1 = (const float*)d_in[5];
    const float* b1     = (const float*)d_in[6];
    const float* W2     = (const float*)d_in[7];
    const float* a_src2 = (const float*)d_in[8];
    const float* a_dst2 = (const float*)d_in[9];
    const float* b2     = (const float*)d_in[10];
    const float* fc1_w  = (const float*)d_in[11];
    const float* fc1_b  = (const float*)d_in[12];
    const float* fc2_w  = (const float*)d_in[13];
    const float* fc2_b  = (const float*)d_in[14];
    float* out = (float*)d_out;

    char* ws = (char*)d_ws;
    size_t off = 0;
    unsigned short* h1  = (unsigned short*)(ws + off); off = align_up(off + (size_t)NN * HD * 2, 256);
    unsigned short* o1  = (unsigned short*)(ws + off); off = align_up(off + (size_t)NN * HD * 2, 256);
    float* asrc = (float*)(ws + off); off = align_up(off + (size_t)NN * 4, 256);
    float* adst = (float*)(ws + off); off = align_up(off + (size_t)NN * 4, 256);
    float* asrc2 = (float*)(ws + off); off = align_up(off + (size_t)NN * 4, 256);
    float* adst2 = (float*)(ws + off); off = align_up(off + (size_t)NN * 4, 256);
    int* cursor = (int*)(ws + off);   off = align_up(off + (size_t)NN * 4, 256);
    unsigned short* slots = (unsigned short*)(ws + off); off = align_up(off + (size_t)NN * SLOTS * 2, 256);
    unsigned short* W1p = (unsigned short*)(ws + off); off = align_up(off + (size_t)HD * KP1 * 2, 256);
    unsigned short* W2p = (unsigned short*)(ws + off); off = align_up(off + (size_t)HD * KP2 * 2, 256);
    (void)ws_size;

    // W cast (fragment-packed) + cursor zeroing (must precede any scatter)
    k_castW<<<CASTW_GRID, 256, 0, stream>>>(W1, W2, W1p, W2p, cursor);

    // layer-1 fp32-direct GEMM || full adjacency scatter
    k_pre<<<GB1 + NSC, 256, 0, stream>>>(x, W1p, h1, asrc, adst, a_src1, a_dst1, NN,
                                         ei, cursor, slots);

    // fused: layer-1 aggregation + layer-2 GEMM (writes o1 = h2, asrc2/adst2)
    k_gatg2<<<GB1, 256, 0, stream>>>(h1, asrc, adst, cursor, slots, b1,
                                     W2p, o1, asrc2, adst2, a_src2, a_dst2, NN);

    // layer-2 aggregation (writes h1 = o2)
    k_gat<<<(NN + 3) / 4, 256, 0, stream>>>(o1, asrc2, adst2, cursor, slots, b2, h1);

    // Pool + FC head
    k_poolfc<<<NG, 512, 0, stream>>>(h1, batch, fc1_w, fc1_b, fc2_w, fc2_b, out);
}

// Round 4
// 290.388 us; speedup vs baseline: 1.0482x; 1.0482x over previous
//
#include <hip/hip_runtime.h>
#include <hip/hip_bf16.h>
#include <math.h>

#define NN 50000
#define NE 800000
#define NET (NE + NN)   // edges + self loops
#define FIN 310
#define HD 128
#define NHID 64
#define NCLS 2
#define NG 128
#define NEG_SLOPE 0.2f
#define KP1 320
#define KP2 128

#define SLOTS 64                    // max degree (Poisson(16)+1; P(>63) ~ 1e-22)
#define NPART 8
#define PART_SZ (NN / NPART)        // 6250
#define EPB 4096
#define NSLICE ((NET + EPB - 1) / EPB)   // 208
#define NSC (NSLICE * NPART)             // 1664 scatter blocks
#define GB1 ((NN + 63) / 64)             // 782 gemm blocks
#define CASTW_GRID ((NE + 255) / 256)    // 3125 blocks: covers edge-pack, W cast, cursor

#define SELU_SCALE 1.0507009873554804934193349852946f
#define SELU_ALPHA 1.6732632423543772848170429916717f

typedef short bf16x8 __attribute__((ext_vector_type(8)));
typedef float f32x4 __attribute__((ext_vector_type(4)));

__device__ __forceinline__ float selu(float x) {
    return SELU_SCALE * (x > 0.f ? x : SELU_ALPHA * (__expf(x) - 1.f));
}
__device__ __forceinline__ float lrelu(float x) {
    return x > 0.f ? x : NEG_SLOPE * x;
}
__device__ __forceinline__ unsigned short f2bf(float f) {
    unsigned int u = __float_as_uint(f);
    u = (u + 0x7fffu + ((u >> 16) & 1u)) >> 16;
    return (unsigned short)u;
}
__device__ __forceinline__ float bf2f(unsigned short b) {
    return __uint_as_float(((unsigned int)b) << 16);
}

// ---------------- W cast+transpose + cursor zero + edge pack ------------------
// Wp[kb][n][8]: the B-fragment for (kb, quad, l16) is 16B contiguous.
// ep[i] = (src<<16)|dst (N < 2^16): the scatter reads ONE u32 array at half
// the bytes of the two int32 arrays, and src comes free with dst. This cuts
// the 8x-replicated per-partition edge scan from ~51 MB to ~26 MB of fabric
// traffic in k_pre (the dominant kernel).

__global__ void k_castW(const float* __restrict__ W1, const float* __restrict__ W2,
                        const int* __restrict__ ei,
                        unsigned short* __restrict__ W1p, unsigned short* __restrict__ W2p,
                        unsigned int* __restrict__ ep, int* __restrict__ cursor) {
    int i = blockIdx.x * blockDim.x + threadIdx.x;
    if (i < NN) cursor[i] = 0;
    const int N1 = HD * KP1;
    if (i < N1) {
        int n = i / KP1, k = i % KP1;
        unsigned short v = (k < FIN) ? f2bf(W1[(size_t)k * HD + n]) : (unsigned short)0;
        W1p[((k >> 3) * HD + n) * 8 + (k & 7)] = v;
    } else if (i - N1 < HD * KP2) {
        int j = i - N1;
        int n = j / KP2, k = j % KP2;
        W2p[((k >> 3) * HD + n) * 8 + (k & 7)] = f2bf(W2[(size_t)k * HD + n]);
    }
    if (i < NE)
        ep[i] = ((unsigned int)ei[i] << 16) | (unsigned int)ei[NE + i];
}

// ---------------- slotted scatter body (r8 variant, packed edges) -------------

__device__ __forceinline__ void scatter_body(int slice, const unsigned int* __restrict__ ep,
                                             int* __restrict__ cursor,
                                             unsigned short* __restrict__ slots,
                                             int part) {
    int lo = part * PART_SZ;
    int base = slice * EPB + threadIdx.x;
#pragma unroll
    for (int k = 0; k < EPB / 256; ++k) {
        int i = base + k * 256;
        if (i >= NET) break;
        int d, s;
        if (i < NE) {
            unsigned int e = ep[i];
            d = (int)(e & 0xffffu);
            s = (int)(e >> 16);
        } else {
            d = i - NE; s = d;      // self loop
        }
        if ((unsigned)(d - lo) < (unsigned)PART_SZ) {
            int pos = atomicAdd(&cursor[d], 1) & (SLOTS - 1);
            slots[(size_t)d * SLOTS + pos] = (unsigned short)s;
        }
    }
}

// ---------------- GEMM epilogue (row-major bf16 C + fused attention dots) -----

#define RGEMM_EPILOGUE                                                         \
    int gr_base = r0 + w * 16 + quad * 4;                                      \
    _Pragma("unroll")                                                          \
    for (int r = 0; r < 4; ++r) {                                              \
        int gr = gr_base + r;                                                  \
        if (gr < M) {                                                          \
            _Pragma("unroll")                                                  \
            for (int nt = 0; nt < 8; ++nt)                                     \
                C[(size_t)gr * HD + nt * 16 + l16] = f2bf(acc[nt][r]);         \
        }                                                                      \
    }                                                                          \
    _Pragma("unroll")                                                          \
    for (int r = 0; r < 4; ++r) {                                              \
        float s1 = 0.f, s2 = 0.f;                                              \
        _Pragma("unroll")                                                      \
        for (int nt = 0; nt < 8; ++nt) {                                       \
            int c = nt * 16 + l16;                                             \
            float v = acc[nt][r];                                              \
            s1 += v * a_src[c];                                                \
            s2 += v * a_dst[c];                                                \
        }                                                                      \
        _Pragma("unroll")                                                      \
        for (int off = 1; off < 16; off <<= 1) {                               \
            s1 += __shfl_xor(s1, off);                                         \
            s2 += __shfl_xor(s2, off);                                         \
        }                                                                      \
        int gr = gr_base + r;                                                  \
        if (l16 == 0 && gr < M) { asrcp[gr] = s1; adstp[gr] = s2; }            \
    }

// ---------------- merged: layer-1 fp32-direct GEMM || full adjacency scatter --
// fp32 A read direct (62 MB) beats the castX round-trip (126 MB) on total
// bytes; next-step register prefetch hides load latency under converts+MFMA.

__global__ __launch_bounds__(256) void k_pre(const float* __restrict__ A,
                                             const unsigned short* __restrict__ Bp,
                                             unsigned short* __restrict__ C,
                                             float* __restrict__ asrcp,
                                             float* __restrict__ adstp,
                                             const float* __restrict__ a_src,
                                             const float* __restrict__ a_dst,
                                             int M,
                                             const unsigned int* __restrict__ ep,
                                             int* __restrict__ cursor,
                                             unsigned short* __restrict__ slots) {
    if (blockIdx.x >= GB1) {
        int b = blockIdx.x - GB1;
        int part = (blockIdx.x + 2) & 7;   // == (b & 7); XCD-pinned partitions
        scatter_body(b >> 3, ep, cursor, slots, part);
        return;
    }
    int t = threadIdx.x;
    int lane = t & 63, w = t >> 6;
    int quad = lane >> 4, l16 = lane & 15;
    int r0 = blockIdx.x * 64;

    int grow = r0 + w * 16 + l16;
    int arow = min(grow, M - 1);
    const float* ap = A + (size_t)arow * FIN + quad * 8;

    f32x4 acc[8] = {};

    float2 c0 = *(const float2*)(ap + 0);
    float2 c1 = *(const float2*)(ap + 2);
    float2 c2 = *(const float2*)(ap + 4);
    float2 c3 = *(const float2*)(ap + 6);
#pragma unroll
    for (int k0 = 0; k0 < 288; k0 += 32) {
        int kn = (k0 < 256) ? k0 + 32 : 256;   // clamped prefetch (L1-hit on last)
        float2 n0 = *(const float2*)(ap + kn + 0);
        float2 n1 = *(const float2*)(ap + kn + 2);
        float2 n2 = *(const float2*)(ap + kn + 4);
        float2 n3 = *(const float2*)(ap + kn + 6);
        union { bf16x8 v; unsigned short u[8]; } af;
        af.u[0] = f2bf(c0.x); af.u[1] = f2bf(c0.y);
        af.u[2] = f2bf(c1.x); af.u[3] = f2bf(c1.y);
        af.u[4] = f2bf(c2.x); af.u[5] = f2bf(c2.y);
        af.u[6] = f2bf(c3.x); af.u[7] = f2bf(c3.y);
        const unsigned short* bbase = Bp + ((size_t)(k0 >> 3) + quad) * (HD * 8) + l16 * 8;
#pragma unroll
        for (int nt = 0; nt < 8; ++nt) {
            bf16x8 bfr = *(const bf16x8*)(bbase + nt * 128);
            acc[nt] = __builtin_amdgcn_mfma_f32_16x16x32_bf16(af.v, bfr, acc[nt], 0, 0, 0);
        }
        c0 = n0; c1 = n1; c2 = n2; c3 = n3;
    }
    {   // tail step k0 = 288: elements 288+quad*8+j, predicated vs FIN
        int kb = 288 + quad * 8;
        const float* rp = A + (size_t)arow * FIN;
        union { bf16x8 v; unsigned short u[8]; } af;
#pragma unroll
        for (int j = 0; j < 8; ++j)
            af.u[j] = (kb + j < FIN) ? f2bf(rp[kb + j]) : (unsigned short)0;
        const unsigned short* bbase = Bp + ((size_t)(288 >> 3) + quad) * (HD * 8) + l16 * 8;
#pragma unroll
        for (int nt = 0; nt < 8; ++nt) {
            bf16x8 bfr = *(const bf16x8*)(bbase + nt * 128);
            acc[nt] = __builtin_amdgcn_mfma_f32_16x16x32_bf16(af.v, bfr, acc[nt], 0, 0, 0);
        }
    }
    RGEMM_EPILOGUE
}

// ---------------- layer-2 GEMM: bf16 A, barrier-free, all-register -----------

__global__ __launch_bounds__(256) void k_gemm2(const unsigned short* __restrict__ A,
                                               const unsigned short* __restrict__ Bp,
                                               unsigned short* __restrict__ C,
                                               float* __restrict__ asrcp,
                                               float* __restrict__ adstp,
                                               const float* __restrict__ a_src,
                                               const float* __restrict__ a_dst,
                                               int M) {
    int t = threadIdx.x;
    int lane = t & 63, w = t >> 6;
    int quad = lane >> 4, l16 = lane & 15;
    int r0 = blockIdx.x * 64;

    int grow = r0 + w * 16 + l16;
    int arow = min(grow, M - 1);
    const unsigned short* aptr = A + (size_t)arow * KP2 + quad * 8;

    f32x4 acc[8] = {};
#pragma unroll
    for (int k0 = 0; k0 < KP2; k0 += 32) {
        bf16x8 af = *(const bf16x8*)(aptr + k0);
        const unsigned short* bbase = Bp + ((size_t)(k0 >> 3) + quad) * (HD * 8) + l16 * 8;
#pragma unroll
        for (int nt = 0; nt < 8; ++nt) {
            bf16x8 bfr = *(const bf16x8*)(bbase + nt * 128);
            acc[nt] = __builtin_amdgcn_mfma_f32_16x16x32_bf16(af, bfr, acc[nt], 0, 0, 0);
        }
    }
    RGEMM_EPILOGUE
}

// ---------------- GAT aggregation (row-major h/o, ushort slots) ---------------
// one wave per node; 4 groups of 16 lanes, uint4 (8 bf16) row loads -> 4 edges
// per instr, x4 unroll (16 gathers in flight).

__global__ __launch_bounds__(256) void k_gat(const unsigned short* __restrict__ h,
                                             const float* __restrict__ asrc,
                                             const float* __restrict__ adst,
                                             const int* __restrict__ degv,
                                             const unsigned short* __restrict__ slots,
                                             const float* __restrict__ bias,
                                             unsigned short* __restrict__ out) {
    int node = blockIdx.x * 4 + (threadIdx.x >> 6);
    int lane = threadIdx.x & 63;
    if (node >= NN) return;
    int g = lane >> 4, cl = lane & 15;
    int deg = degv[node];
    float adsti = adst[node];

    float2 acc2[4] = {};

    int cnt = min(deg, SLOTS);
    int s_c = 0; float p_c = 0.f;
    if (lane < cnt) {
        s_c = slots[(size_t)node * SLOTS + lane];
        p_c = __expf(lrelu(asrc[s_c] + adsti));
    }
    float den_l = p_c;
    int nt = (cnt + 3) >> 2;   // edge-quads
    for (int t = 0; t < nt; t += 4) {
        float pv[4]; uint4 hv[4];
#pragma unroll
        for (int u = 0; u < 4; ++u) {
            int tt = t + u;
            bool valid = tt < nt;
            int e = (4 * tt + g) & 63;
            int s = __shfl(s_c, e);
            float p = __shfl(p_c, e);
            int sa = valid ? s : 0;
            pv[u] = valid ? p : 0.f;
            hv[u] = *(const uint4*)(h + (size_t)sa * HD + cl * 8);
        }
#pragma unroll
        for (int u = 0; u < 4; ++u) {
            float p = pv[u];
            unsigned int w0 = hv[u].x, w1 = hv[u].y, w2 = hv[u].z, w3 = hv[u].w;
            acc2[0].x += p * __uint_as_float(w0 << 16);
            acc2[0].y += p * __uint_as_float(w0 & 0xffff0000u);
            acc2[1].x += p * __uint_as_float(w1 << 16);
            acc2[1].y += p * __uint_as_float(w1 & 0xffff0000u);
            acc2[2].x += p * __uint_as_float(w2 << 16);
            acc2[2].y += p * __uint_as_float(w2 & 0xffff0000u);
            acc2[3].x += p * __uint_as_float(w3 << 16);
            acc2[3].y += p * __uint_as_float(w3 & 0xffff0000u);
        }
    }
#pragma unroll
    for (int k = 0; k < 4; ++k) {
        acc2[k].x += __shfl_xor(acc2[k].x, 16);
        acc2[k].y += __shfl_xor(acc2[k].y, 16);
        acc2[k].x += __shfl_xor(acc2[k].x, 32);
        acc2[k].y += __shfl_xor(acc2[k].y, 32);
    }
#pragma unroll
    for (int off = 32; off; off >>= 1)
        den_l += __shfl_xor(den_l, off);

    if (g == 0) {
        float inv = 1.f / den_l;
        int c0 = cl * 8;
        float4 b0 = *(const float4*)(bias + c0);
        float4 b1 = *(const float4*)(bias + c0 + 4);
        float v0 = selu(acc2[0].x * inv + b0.x);
        float v1 = selu(acc2[0].y * inv + b0.y);
        float v2 = selu(acc2[1].x * inv + b0.z);
        float v3 = selu(acc2[1].y * inv + b0.w);
        float v4 = selu(acc2[2].x * inv + b1.x);
        float v5 = selu(acc2[2].y * inv + b1.y);
        float v6 = selu(acc2[3].x * inv + b1.z);
        float v7 = selu(acc2[3].y * inv + b1.w);
        uint4 pk;
        pk.x = (unsigned int)f2bf(v0) | ((unsigned int)f2bf(v1) << 16);
        pk.y = (unsigned int)f2bf(v2) | ((unsigned int)f2bf(v3) << 16);
        pk.z = (unsigned int)f2bf(v4) | ((unsigned int)f2bf(v5) << 16);
        pk.w = (unsigned int)f2bf(v6) | ((unsigned int)f2bf(v7) << 16);
        *(uint4*)(out + (size_t)node * HD + c0) = pk;
    }
}

// ---------------- pooling + FC head (fused, one block per graph) ----------------

__device__ __forceinline__ int lower_bound_i(const int* a, int n, int key) {
    int lo = 0, hi = n;
    while (lo < hi) {
        int mid = (lo + hi) >> 1;
        if (a[mid] < key) lo = mid + 1; else hi = mid;
    }
    return lo;
}

__global__ __launch_bounds__(512) void k_poolfc(const unsigned short* __restrict__ x,
                                                const int* __restrict__ batch,
                                                const float* __restrict__ w1,
                                                const float* __restrict__ b1,
                                                const float* __restrict__ w2,
                                                const float* __restrict__ b2,
                                                float* __restrict__ out) {
    int g = blockIdx.x;
    int t = threadIdx.x;
    __shared__ int lo_s, hi_s;
    __shared__ float red[512];
    __shared__ float pooled_s[128];
    if (t == 0) {
        lo_s = lower_bound_i(batch, NN, g);
        hi_s = lower_bound_i(batch, NN, g + 1);
    }
    __syncthreads();
    int lo = lo_s, hi = hi_s;
    float acc = 0.f;
    for (int n = lo + (t >> 7); n < hi; n += 4)
        acc += bf2f(x[(size_t)n * HD + (t & 127)]);
    red[t] = acc;
    __syncthreads();
    if (t < 128) {
        float v = red[t] + red[t + 128] + red[t + 256] + red[t + 384];
        pooled_s[t] = selu(v / fmaxf((float)(hi - lo), 1.f));
    }
    __syncthreads();
    if (t < 64) {
        float z = 0.f;
#pragma unroll 8
        for (int k = 0; k < HD; ++k) z += pooled_s[k] * w1[k * NHID + t];
        z = selu(z + b1[t]);
        float p0 = z * w2[t * NCLS + 0];
        float p1 = z * w2[t * NCLS + 1];
        for (int off = 32; off; off >>= 1) {
            p0 += __shfl_down(p0, off);
            p1 += __shfl_down(p1, off);
        }
        if (t == 0) {
            float l0 = p0 + b2[0], l1 = p1 + b2[1];
            float m = fmaxf(l0, l1);
            float lse = m + __logf(__expf(l0 - m) + __expf(l1 - m));
            out[g * NCLS + 0] = l0 - lse;
            out[g * NCLS + 1] = l1 - lse;
        }
    }
}

// ---------------- launch ----------------

static inline size_t align_up(size_t v, size_t a) { return (v + a - 1) / a * a; }

extern "C" void kernel_launch(void* const* d_in, const int* in_sizes, int n_in,
                              void* d_out, int out_size, void* d_ws, size_t ws_size,
                              hipStream_t stream) {
    const float* x      = (const float*)d_in[0];
    const int*   ei     = (const int*)d_in[1];
    const int*   batch  = (const int*)d_in[2];
    const float* W1     = (const float*)d_in[3];
    const float* a_src1 = (const float*)d_in[4];
    const float* a_dst1 = (const float*)d_in[5];
    const float* b1     = (const float*)d_in[6];
    const float* W2     = (const float*)d_in[7];
    const float* a_src2 = (const float*)d_in[8];
    const float* a_dst2 = (const float*)d_in[9];
    const float* b2     = (const float*)d_in[10];
    const float* fc1_w  = (const float*)d_in[11];
    const float* fc1_b  = (const float*)d_in[12];
    const float* fc2_w  = (const float*)d_in[13];
    const float* fc2_b  = (const float*)d_in[14];
    float* out = (float*)d_out;

    char* ws = (char*)d_ws;
    size_t off = 0;
    unsigned short* h1  = (unsigned short*)(ws + off); off = align_up(off + (size_t)NN * HD * 2, 256);
    unsigned short* o1  = (unsigned short*)(ws + off); off = align_up(off + (size_t)NN * HD * 2, 256);
    float* asrc = (float*)(ws + off); off = align_up(off + (size_t)NN * 4, 256);
    float* adst = (float*)(ws + off); off = align_up(off + (size_t)NN * 4, 256);
    int* cursor = (int*)(ws + off);   off = align_up(off + (size_t)NN * 4, 256);
    unsigned short* slots = (unsigned short*)(ws + off); off = align_up(off + (size_t)NN * SLOTS * 2, 256);
    unsigned short* W1p = (unsigned short*)(ws + off); off = align_up(off + (size_t)HD * KP1 * 2, 256);
    unsigned short* W2p = (unsigned short*)(ws + off); off = align_up(off + (size_t)HD * KP2 * 2, 256);
    unsigned int* epack = (unsigned int*)(ws + off); off = align_up(off + (size_t)NE * 4, 256);
    (void)ws_size;

    // W cast (fragment-packed) + cursor zero + edge pack (u16 pairs)
    k_castW<<<CASTW_GRID, 256, 0, stream>>>(W1, W2, ei, W1p, W2p, epack, cursor);

    // layer-1 fp32-direct GEMM || full adjacency scatter (packed edges)
    k_pre<<<GB1 + NSC, 256, 0, stream>>>(x, W1p, h1, asrc, adst, a_src1, a_dst1, NN,
                                         epack, cursor, slots);

    // Layer 1 aggregation
    k_gat<<<(NN + 3) / 4, 256, 0, stream>>>(h1, asrc, adst, cursor, slots, b1, o1);

    // Layer 2
    k_gemm2<<<GB1, 256, 0, stream>>>(o1, W2p, h1, asrc, adst, a_src2, a_dst2, NN);
    k_gat<<<(NN + 3) / 4, 256, 0, stream>>>(h1, asrc, adst, cursor, slots, b2, o1);

    // Pool + FC head
    k_poolfc<<<NG, 512, 0, stream>>>(o1, batch, fc1_w, fc1_b, fc2_w, fc2_b, out);
}